// Round 14
// baseline (95.434 us; speedup 1.0000x reference)
//
#include <hip/hip_runtime.h>
#include <math.h>

#define BATCH 16
#define H 1024
#define W 1024
#define NTILES 8192      // 16 img * 512 tiles (32x64); 1 tile per WAVE now
#define NBANDS (NTILES * 4)   // 8-row x 64-col bands
#define NBLK 4096        // 128-thread blocks, 2 waves = 2 tiles each
#define CAP 4096
#define TOPK 2048
#define BCW 12           // per-band candidate cap (8-separation bound: 8)

#define SYNC_WAVE() do { \
  __builtin_amdgcn_wave_barrier(); \
  asm volatile("s_waitcnt lgkmcnt(0)" ::: "memory"); \
  __builtin_amdgcn_sched_barrier(0); \
} while (0)

struct WS {
  float pt1[NBANDS];
  int   pmc[NBANDS];
  int   band_cnt[NBANDS];
  int   cand_count[BATCH];
  float corr_part[BATCH * 64];
  float band_val[NBANDS * BCW];
  int   band_idx[NBANDS * BCW];
  float ccand_val[BATCH * CAP];
  int   ccand_idx[BATCH * CAP];
};

// ks=7 sigma=1 normalized Gaussian (validated absmax 0.0 R1-R13)
__constant__ float GW[7] = {
  0.004433048175f, 0.054005582623f, 0.242036229376f, 0.399050279652f,
  0.242036229376f, 0.054005582623f, 0.004433048175f
};

__device__ __forceinline__ float4 max4(float4 a, float4 b) {
  float4 r;
  r.x = fmaxf(a.x, b.x); r.y = fmaxf(a.y, b.y);
  r.z = fmaxf(a.z, b.z); r.w = fmaxf(a.w, b.w);
  return r;
}

// One WAVE per 32x64 tile: private 46x21-f4 LDS slice, zero block barriers,
// loads pipelined across band computes (no vmcnt(0) drains anywhere).
__global__ __launch_bounds__(128, 2) void k_nms(const float* __restrict__ score1,
                                                const float* __restrict__ score2,
                                                const int* __restrict__ mask,
                                                WS* __restrict__ ws) {
  __shared__ float4 halo[2][46][21];   // 30912 B -> 5 blocks/CU
  const int tid = threadIdx.x;
  const int w = tid >> 6, l = tid & 63;

  // bijective XCD swizzle over 4096 blocks
  const int blk = (blockIdx.x & 7) * (NBLK / 8) + (blockIdx.x >> 3);
  const int t = (blk << 1) + w;        // tile id 0..8191 (same mapping as R7-R13)
  const int b  = t >> 9;
  const int tt = t & 511;
  const int ty0 = (tt >> 4) << 5;
  const int tx0 = (tt & 15) << 6;
  const size_t ibase = (size_t)b * ((size_t)H * W);
  const float* s2 = score2 + ibase;
  const int rl = l >> 3;               // band-local row 0..7
  const int c8 = l & 7;                // col group

  // ---- 1) issue s1/mask for ALL 4 bands (FIRST in vmcnt order) ----
  float4 s1a[4], s1b[4]; int4 mka[4], mkb[4];
  #pragma unroll
  for (int k = 0; k < 4; k++) {
    const size_t pb = ibase + (size_t)(ty0 + (k << 3) + rl) * W + tx0 + (c8 << 3);
    s1a[k] = *(const float4*)(score1 + pb);
    s1b[k] = *(const float4*)(score1 + pb + 4);
    mka[k] = *(const int4*)(mask + pb);
    mkb[k] = *(const int4*)(mask + pb + 4);
  }

  // ---- 2) issue halo rows 0..21 (slots 0..439), clamped vector loads ----
  float4 stA[7]; int rA[7], cA[7];
  #pragma unroll
  for (int k = 0; k < 7; k++) {
    const int slot = l + (k << 6);
    if (slot < 440) {
      const int r = slot / 20, c = slot - r * 20;
      rA[k] = r; cA[k] = c;
      const int gy = ty0 - 7 + r, gx = tx0 - 8 + (c << 2);
      const bool ok = (gy >= 0) & (gy < H) & (gx >= 0) & (gx < W);
      const int gyc = min(max(gy, 0), H - 1);
      const int gxc = ok ? gx : 0;
      float4 v = *(const float4*)(s2 + (size_t)gyc * W + gxc);
      if (!ok) v = make_float4(-INFINITY, -INFINITY, -INFINITY, -INFINITY);
      stA[k] = v;
    }
  }

  // ---- 3) dense terms x4 (waits only s1/mask; halo loads stay in flight) ----
  float t1[4]; int mcnt[4]; unsigned int mbits[4];
  #pragma unroll
  for (int k = 0; k < 4; k++) {
    t1[k] = 0.f; mcnt[k] = 0; mbits[k] = 0;
    const float sc_[8] = {s1a[k].x, s1a[k].y, s1a[k].z, s1a[k].w,
                          s1b[k].x, s1b[k].y, s1b[k].z, s1b[k].w};
    const int   mm[8] = {mka[k].x, mka[k].y, mka[k].z, mka[k].w,
                         mkb[k].x, mkb[k].y, mkb[k].z, mkb[k].w};
    #pragma unroll
    for (int j = 0; j < 8; j++) {
      if (mm[j]) { t1[k] = fmaf(sc_[j], sc_[j], t1[k]); mcnt[k]++; mbits[k] |= (1u << j); }
    }
  }

  // ---- 4) issue halo rows 22..45 (slots 440..919) ----
  float4 stB[8]; int rB[8], cB[8];
  #pragma unroll
  for (int k = 0; k < 8; k++) {
    const int slot = 440 + l + (k << 6);
    if (slot < 920) {
      const int r = slot / 20, c = slot - r * 20;
      rB[k] = r; cB[k] = c;
      const int gy = ty0 - 7 + r, gx = tx0 - 8 + (c << 2);
      const bool ok = (gy >= 0) & (gy < H) & (gx >= 0) & (gx < W);
      const int gyc = min(max(gy, 0), H - 1);
      const int gxc = ok ? gx : 0;
      float4 v = *(const float4*)(s2 + (size_t)gyc * W + gxc);
      if (!ok) v = make_float4(-INFINITY, -INFINITY, -INFINITY, -INFINITY);
      stB[k] = v;
    }
  }

  // ---- 5) stage part 1 (waits only its own loads; part-2 loads keep flying) ----
  #pragma unroll
  for (int k = 0; k < 7; k++) {
    if (l + (k << 6) < 440) halo[w][rA[k]][cA[k]] = stA[k];
  }
  SYNC_WAVE();

  // ---- per-band body (wave-local; pure LDS/VALU) ----
  auto band_body = [&](int k) {
    const int s0 = k << 3;             // slice-row offset of this band's outputs
    float4 vr0, vr1, vr2, vr3;
    int R0 = 0, cg = 0;
    if (l < 40) {
      const int r2 = l / 20;
      cg = l - r2 * 20;
      R0 = s0 + (r2 << 2);
      float4 core = halo[w][R0 + 3][cg];
      #pragma unroll
      for (int k2 = 4; k2 <= 14; k2++) core = max4(core, halo[w][R0 + k2][cg]);
      const float4 h0 = halo[w][R0][cg], h1 = halo[w][R0 + 1][cg], h2 = halo[w][R0 + 2][cg];
      const float4 h15 = halo[w][R0 + 15][cg], h16 = halo[w][R0 + 16][cg], h17 = halo[w][R0 + 17][cg];
      const float4 p2 = h2, p1 = max4(h1, p2), p0 = max4(h0, p1);
      const float4 sf15 = h15, sf16 = max4(sf15, h16), sf17 = max4(sf16, h17);
      vr0 = max4(core, p0);
      vr1 = max4(max4(core, p1), sf15);
      vr2 = max4(max4(core, p2), sf16);
      vr3 = max4(core, sf17);
    }
    // capture raw score2 centers (slice rows s0+7..s0+14) before overwrite
    const float4 cva = halo[w][s0 + rl + 7][(c8 << 1) + 2];
    const float4 cvb = halo[w][s0 + rl + 7][(c8 << 1) + 3];
    SYNC_WAVE();
    if (l < 40) {
      halo[w][R0 + 0][cg] = vr0;
      halo[w][R0 + 1][cg] = vr1;
      halo[w][R0 + 2][cg] = vr2;
      halo[w][R0 + 3][cg] = vr3;
    }
    SYNC_WAVE();
    // horizontal 15-max in registers
    float r[24];
    #pragma unroll
    for (int g = 0; g < 6; g++) {
      float4 v = halo[w][s0 + rl][(c8 << 1) + g];
      r[4 * g + 0] = v.x; r[4 * g + 1] = v.y; r[4 * g + 2] = v.z; r[4 * g + 3] = v.w;
    }
    float core = r[8];
    #pragma unroll
    for (int k2 = 9; k2 <= 15; k2++) core = fmaxf(core, r[k2]);
    const float q7 = r[7];
    const float q6 = fmaxf(r[6], q7);
    const float q5 = fmaxf(r[5], q6);
    const float q4 = fmaxf(r[4], q5);
    const float q3 = fmaxf(r[3], q4);
    const float q2 = fmaxf(r[2], q3);
    const float q1 = fmaxf(r[1], q2);
    float sa[7];
    sa[0] = r[16];
    #pragma unroll
    for (int k2 = 1; k2 < 7; k2++) sa[k2] = fmaxf(sa[k2 - 1], r[16 + k2]);
    float pooled[8];
    pooled[0] = fmaxf(core, q1);
    pooled[1] = fmaxf(fmaxf(core, q2), sa[0]);
    pooled[2] = fmaxf(fmaxf(core, q3), sa[1]);
    pooled[3] = fmaxf(fmaxf(core, q4), sa[2]);
    pooled[4] = fmaxf(fmaxf(core, q5), sa[3]);
    pooled[5] = fmaxf(fmaxf(core, q6), sa[4]);
    pooled[6] = fmaxf(fmaxf(core, q7), sa[5]);
    pooled[7] = fmaxf(core, sa[6]);

    const float cc[8] = {cva.x, cva.y, cva.z, cva.w, cvb.x, cvb.y, cvb.z, cvb.w};
    int cj = -1; float cv = 0.f;
    #pragma unroll
    for (int j = 0; j < 8; j++) {
      if (((mbits[k] >> j) & 1u) && cj < 0) {
        const float s = cc[j];
        if (s == pooled[j] && s > 0.f) { cj = j; cv = s; }
      }
    }
    const int band = (t << 2) + k;
    const unsigned long long bal = __ballot(cj >= 0);
    if (cj >= 0) {
      const int pos = (int)__popcll(bal & ((1ull << l) - 1ull));
      if (pos < BCW) {
        ws->band_val[band * BCW + pos] = cv;
        ws->band_idx[band * BCW + pos] = (ty0 + s0 + rl) * W + tx0 + (c8 << 3) + cj;
      }
    }
    float rt1 = t1[k]; int rmc = mcnt[k];
    #pragma unroll
    for (int off = 32; off > 0; off >>= 1) {
      rt1 += __shfl_down(rt1, off);
      rmc += __shfl_down(rmc, off);
    }
    if (l == 0) {
      int nc = (int)__popcll(bal); if (nc > BCW) nc = BCW;
      ws->band_cnt[band] = nc;
      ws->pt1[band] = rt1;
      ws->pmc[band] = rmc;
    }
  };

  // ---- 6) band 0 computes while rows 22..45 are still in flight ----
  band_body(0);

  // ---- 7) stage part 2, then bands 1..3 (no remaining memory waits) ----
  #pragma unroll
  for (int k = 0; k < 8; k++) {
    if (440 + l + (k << 6) < 920) halo[w][rB[k]][cB[k]] = stB[k];
  }
  SYNC_WAVE();

  band_body(1);
  band_body(2);
  band_body(3);
}

// One block per image: single compaction pass band arrays -> contiguous ccand.
__global__ __launch_bounds__(256) void k_compact(WS* __restrict__ ws) {
  const int b = blockIdx.x;
  const int tid = threadIdx.x;
  const int lane = tid & 63, w = tid >> 6;
  __shared__ int wt[4];

  const int base = b * 2048 + tid * 8;
  int c[8]; int csum = 0;
  #pragma unroll
  for (int u = 0; u < 8; u++) {
    int x = ws->band_cnt[base + u];
    if (x > BCW) x = BCW;
    c[u] = x; csum += x;
  }
  int v = csum;
  #pragma unroll
  for (int off = 1; off < 64; off <<= 1) {
    int u2 = __shfl_up(v, off);
    if (lane >= off) v += u2;
  }
  if (lane == 63) wt[w] = v;
  __syncthreads();
  int wo = 0;
  #pragma unroll
  for (int k = 0; k < 4; k++) if (k < w) wo += wt[k];
  const int excl = v - csum + wo;
  float* dv = ws->ccand_val + b * CAP;
  int*   di = ws->ccand_idx + b * CAP;
  if (tid == 255) {
    int tot = excl + csum;
    if (tot > CAP) tot = CAP;
    ws->cand_count[b] = tot;
    #pragma unroll
    for (int u = 0; u < 3; u++)
      if (tot + u < CAP) dv[tot + u] = 0.f;
  }
  int off = excl;
  #pragma unroll
  for (int u = 0; u < 8; u++) {
    const float* sv = ws->band_val + (size_t)(base + u) * BCW;
    const int*   si = ws->band_idx + (size_t)(base + u) * BCW;
    for (int j = 0; j < c[u]; j++) {
      if (off < CAP) { dv[off] = sv[j]; di[off] = si[j]; }
      off++;
    }
  }
}

// Exact-rank + stamp from compacted arrays.
__global__ __launch_bounds__(256, 4) void k_rankstamp(const float* __restrict__ score1,
                                                      const int* __restrict__ mask,
                                                      WS* __restrict__ ws) {
  const int blk = (blockIdx.x & 7) * 128 + (blockIdx.x >> 3);
  const int b = blk >> 6;
  const int slice = blk & 63;
  int n = ws->cand_count[b]; if (n > CAP) n = CAP;
  const int i0 = slice << 6;
  if (i0 >= n) {
    if (threadIdx.x == 0) ws->corr_part[b * 64 + slice] = 0.f;
    return;
  }
  __shared__ __align__(16) float sval[CAP];
  __shared__ __align__(16) int   sidx[CAP];
  __shared__ int   s_prank[4][64];
  __shared__ int   s_keys[64];
  __shared__ int   s_nk;
  __shared__ float cred[4];
  const int tid = threadIdx.x;
  const int w = tid >> 6, l = tid & 63;
  const int nf4 = (n + 3) >> 2;

  const float4* gv = (const float4*)(ws->ccand_val + b * CAP);
  const int4*   gi = (const int4*)(ws->ccand_idx + b * CAP);
  for (int j = tid; j < nf4; j += 256) {
    ((float4*)sval)[j] = gv[j];
    ((int4*)sidx)[j]   = gi[j];
  }
  __syncthreads();

  const float vi = sval[i0 + l];
  const int   xi = sidx[i0 + l];
  const int q = (nf4 + 3) >> 2;
  int lo = w * q; if (lo > nf4) lo = nf4;
  int hi = lo + q; if (hi > nf4) hi = nf4;
  int rank = 0;
  int j = lo;
  for (; j + 4 <= hi; j += 4) {
    #pragma unroll
    for (int u = 0; u < 4; u++) {
      const float4 vv = ((const float4*)sval)[j + u];
      const int4  iv = ((const int4*)sidx)[j + u];
      rank += (vv.x > vi) + (vv.y > vi) + (vv.z > vi) + (vv.w > vi);
      rank += (vv.x == vi && iv.x < xi);
      rank += (vv.y == vi && iv.y < xi);
      rank += (vv.z == vi && iv.z < xi);
      rank += (vv.w == vi && iv.w < xi);
    }
  }
  for (; j < hi; j++) {
    const float4 vv = ((const float4*)sval)[j];
    const int4  iv = ((const int4*)sidx)[j];
    rank += (vv.x > vi) + (vv.y > vi) + (vv.z > vi) + (vv.w > vi);
    rank += (vv.x == vi && iv.x < xi);
    rank += (vv.y == vi && iv.y < xi);
    rank += (vv.z == vi && iv.z < xi);
    rank += (vv.w == vi && iv.w < xi);
  }
  s_prank[w][l] = rank;
  __syncthreads();

  if (tid < 64) {
    const int rtot = s_prank[0][tid] + s_prank[1][tid] + s_prank[2][tid] + s_prank[3][tid];
    const bool sel = (i0 + tid < n) && (rtot < TOPK);
    const unsigned long long bal = __ballot(sel);
    if (sel) {
      const int pos = __popcll(bal & ((1ull << tid) - 1ull));
      s_keys[pos] = sidx[i0 + tid];
    }
    if (tid == 0) s_nk = (int)__popcll(bal);
  }
  __syncthreads();
  const int nk = s_nk;

  float contrib = 0.f;
  const int sub = tid & 7;
  const size_t ib2 = (size_t)b * ((size_t)H * W);
  #pragma unroll
  for (int rnd = 0; rnd < 2; rnd++) {
    const int k = (tid >> 3) + (rnd << 5);
    if (k < nk && sub < 7) {
      const int ck = s_keys[k];
      const int cy = ck >> 10, cx = ck & 1023;
      const int py = cy + sub - 3;
      const float wy = GW[sub] * ((py >= 0 && py < H) ? 1.f : 0.f);
      const int pyc = min(max(py, 0), H - 1);
      const float* s1r = score1 + ib2 + (size_t)pyc * W;
      const int*   mr  = mask   + ib2 + (size_t)pyc * W;
      #pragma unroll
      for (int dx = -3; dx <= 3; dx++) {
        const int px = cx + dx;
        const float wv = wy * GW[dx + 3] * ((px >= 0 && px < W) ? 1.f : 0.f);
        const int pxc = min(max(px, 0), W - 1);
        const float mf = (mr[pxc] != 0) ? 1.f : 0.f;
        contrib += mf * wv * (wv - 2.f * s1r[pxc]);
      }
    }
  }
  #pragma unroll
  for (int off2 = 32; off2 > 0; off2 >>= 1) contrib += __shfl_down(contrib, off2);
  if (l == 0) cred[w] = contrib;
  __syncthreads();
  if (tid == 0)
    ws->corr_part[b * 64 + slice] = (cred[0] + cred[1]) + (cred[2] + cred[3]);
}

// One block, 1024 threads: wave b reduces image b's partials.
__global__ __launch_bounds__(1024) void k_final(WS* __restrict__ ws, float* __restrict__ out) {
  const int tid = threadIdx.x;
  const int b = tid >> 6, l = tid & 63;
  __shared__ double sD[BATCH];

  double tsum = 0.0; long long msum = 0;
  const float4* pv = (const float4*)(ws->pt1 + b * 2048);
  const int4*   pm = (const int4*)(ws->pmc + b * 2048);
  #pragma unroll
  for (int k = 0; k < 8; k++) {
    const float4 f = pv[l + (k << 6)];
    const int4   m = pm[l + (k << 6)];
    tsum += (double)f.x + (double)f.y + (double)f.z + (double)f.w;
    msum += (long long)(m.x + m.y + m.z + m.w);
  }
  double csum = (double)ws->corr_part[b * 64 + l];
  #pragma unroll
  for (int off = 32; off > 0; off >>= 1) {
    tsum += __shfl_down(tsum, off);
    msum += __shfl_down(msum, off);
    csum += __shfl_down(csum, off);
  }
  if (l == 0) {
    double denom = (double)msum;
    if (denom < 1e-8) denom = 1e-8;
    sD[b] = (tsum + csum) / denom;
  }
  __syncthreads();
  if (tid == 0) {
    double acc = 0.0;
    #pragma unroll
    for (int k = 0; k < BATCH; k++) acc += sD[k];
    out[0] = (float)(acc / BATCH);
  }
}

extern "C" void kernel_launch(void* const* d_in, const int* in_sizes, int n_in,
                              void* d_out, int out_size, void* d_ws, size_t ws_size,
                              hipStream_t stream) {
  const float* score1 = (const float*)d_in[0];
  const float* score2 = (const float*)d_in[1];
  const int*   mask   = (const int*)d_in[2];
  float* out = (float*)d_out;
  WS* ws = (WS*)d_ws;

  k_nms<<<NBLK, 128, 0, stream>>>(score1, score2, mask, ws);
  k_compact<<<BATCH, 256, 0, stream>>>(ws);
  k_rankstamp<<<BATCH * 64, 256, 0, stream>>>(score1, mask, ws);
  k_final<<<1, 1024, 0, stream>>>(ws, out);
}

// Round 15
// 82.343 us; speedup vs baseline: 1.1590x; 1.1590x over previous
//
#include <hip/hip_runtime.h>
#include <math.h>

#define BATCH 16
#define H 1024
#define W 1024
#define HR 46            // halo rows = 32 + 14
#define CGW 20           // float4 groups per halo row (80 floats: tx0-8 .. tx0+71)
#define CGP 21           // padded stride (336B)
#define NTILES 8192      // 16 img * 512 tiles (32x64 each)
#define CAP 4096
#define TOPK 2048
#define BCAP 40          // per-tile candidate cap (8-separation bound: 32)

struct WS {
  double term1[BATCH];
  double corr[BATCH];
  unsigned int masksum[BATCH];
  int cand_count[BATCH];
  int   tile_cnt[NTILES];          // stored (not accumulated) by k_nms every call
  float pt1[NTILES * 4];           // per-wave dense partials (always written)
  int   pmc[NTILES * 4];
  float tile_val[NTILES * BCAP];
  int   tile_idx[NTILES * BCAP];
  float ccand_val[BATCH * CAP];    // [0..cand_count) + 3-elem zero pad written by k_compact
  int   ccand_idx[BATCH * CAP];
};

// ks=7 sigma=1 normalized Gaussian (validated absmax 0.0 R1-R14)
__constant__ float GW[7] = {
  0.004433048175f, 0.054005582623f, 0.242036229376f, 0.399050279652f,
  0.242036229376f, 0.054005582623f, 0.004433048175f
};

__device__ __forceinline__ float4 max4(float4 a, float4 b) {
  float4 r;
  r.x = fmaxf(a.x, b.x); r.y = fmaxf(a.y, b.y);
  r.z = fmaxf(a.z, b.z); r.w = fmaxf(a.w, b.w);
  return r;
}

// One block per 32x64 tile. XCD-chunked swizzle; 3 barriers; zero global atomics.
// Best-measured k_nms variant (R7 bench: 72-75us, total 82.2us).
__global__ __launch_bounds__(256, 6) void k_nms(const float* __restrict__ score1,
                                                const float* __restrict__ score2,
                                                const int* __restrict__ mask,
                                                WS* __restrict__ ws) {
  __shared__ float4 halo[HR][CGP];
  __shared__ float4 rmax[32][CGP];
  __shared__ float s_cv[BCAP];
  __shared__ int   s_ci[BCAP];
  __shared__ int   s_cnt;
  const int tid = threadIdx.x;

  // bijective XCD swizzle: hw blocks i, i+8 (same XCD) -> adjacent tiles
  const int t = (blockIdx.x & 7) * (NTILES / 8) + (blockIdx.x >> 3);
  const int b  = t >> 9;
  const int tt = t & 511;
  const int ty0 = (tt >> 4) << 5;
  const int tx0 = (tt & 15) << 6;
  const size_t ibase = (size_t)b * ((size_t)H * W);

  if (tid == 0) s_cnt = 0;

  // ---- phase 1: issue all global loads ----
  float4 st[4];
  int hr_[4], hc_[4];
  const bool interior = (ty0 >= 7) && (ty0 + 38 < H) && (tx0 >= 8) && (tx0 + 71 < W);
  if (interior) {
    #pragma unroll
    for (int k = 0; k < 4; k++) {
      int i = tid + (k << 8);
      if (i < HR * CGW) {
        int r = i / CGW, c = i - r * CGW;
        hr_[k] = r; hc_[k] = c;
        st[k] = *((const float4*)(score2 + ibase + (size_t)(ty0 - 7 + r) * W + (tx0 - 8)) + c);
      }
    }
  } else {
    #pragma unroll
    for (int k = 0; k < 4; k++) {
      int i = tid + (k << 8);
      if (i < HR * CGW) {
        int r = i / CGW, c = i - r * CGW;
        hr_[k] = r; hc_[k] = c;
        int gy = ty0 - 7 + r, gx = tx0 - 8 + (c << 2);
        float vv[4] = {-INFINITY, -INFINITY, -INFINITY, -INFINITY};
        if (gy >= 0 && gy < H) {
          const float* rp = score2 + ibase + (size_t)gy * W;
          #pragma unroll
          for (int u = 0; u < 4; u++) {
            int gxu = gx + u;
            if (gxu >= 0 && gxu < W) vv[u] = rp[gxu];
          }
        }
        st[k] = make_float4(vv[0], vv[1], vv[2], vv[3]);
      }
    }
  }
  const int prow = tid >> 3;          // 0..31
  const int c8   = tid & 7;           // 0..7
  const size_t pb = ibase + (size_t)(ty0 + prow) * W + tx0 + (c8 << 3);
  const float4 s1a = *(const float4*)(score1 + pb);
  const float4 s1b = *(const float4*)(score1 + pb + 4);
  const int4  mka = *(const int4*)(mask + pb);
  const int4  mkb = *(const int4*)(mask + pb + 4);

  #pragma unroll
  for (int k = 0; k < 4; k++) {
    int i = tid + (k << 8);
    if (i < HR * CGW) halo[hr_[k]][hc_[k]] = st[k];
  }
  __syncthreads();

  // ---- phase 2: vertical 15-max -> rmax (160 active threads) ----
  if (tid < 160) {
    const int rr = tid / 20;
    const int cg = tid - rr * 20;
    const int R0 = rr << 2;
    float4 core = halo[R0 + 3][cg];
    #pragma unroll
    for (int k = 4; k <= 14; k++) core = max4(core, halo[R0 + k][cg]);
    const float4 h0 = halo[R0][cg], h1 = halo[R0 + 1][cg], h2 = halo[R0 + 2][cg];
    const float4 h15 = halo[R0 + 15][cg], h16 = halo[R0 + 16][cg], h17 = halo[R0 + 17][cg];
    const float4 p2 = h2, p1 = max4(h1, p2), p0 = max4(h0, p1);
    const float4 sf15 = h15, sf16 = max4(sf15, h16), sf17 = max4(sf16, h17);
    rmax[R0 + 0][cg] = max4(core, p0);
    rmax[R0 + 1][cg] = max4(max4(core, p1), sf15);
    rmax[R0 + 2][cg] = max4(max4(core, p2), sf16);
    rmax[R0 + 3][cg] = max4(core, sf17);
  }

  // dense term from registers (overlaps phase-2 latency)
  float t1 = 0.f; int mcnt = 0; unsigned int mbits = 0;
  {
    const float sc[8] = {s1a.x, s1a.y, s1a.z, s1a.w, s1b.x, s1b.y, s1b.z, s1b.w};
    const int   mm[8] = {mka.x, mka.y, mka.z, mka.w, mkb.x, mkb.y, mkb.z, mkb.w};
    #pragma unroll
    for (int j = 0; j < 8; j++) {
      if (mm[j]) { t1 = fmaf(sc[j], sc[j], t1); mcnt++; mbits |= (1u << j); }
    }
  }
  __syncthreads();

  // ---- phase 3: horizontal 15-max in registers + emit to LDS ----
  float r[24];
  #pragma unroll
  for (int g = 0; g < 6; g++) {
    float4 v = rmax[prow][(c8 << 1) + g];
    r[4 * g + 0] = v.x; r[4 * g + 1] = v.y; r[4 * g + 2] = v.z; r[4 * g + 3] = v.w;
  }
  float core = r[8];
  #pragma unroll
  for (int k = 9; k <= 15; k++) core = fmaxf(core, r[k]);
  const float q7 = r[7];
  const float q6 = fmaxf(r[6], q7);
  const float q5 = fmaxf(r[5], q6);
  const float q4 = fmaxf(r[4], q5);
  const float q3 = fmaxf(r[3], q4);
  const float q2 = fmaxf(r[2], q3);
  const float q1 = fmaxf(r[1], q2);
  float sa[7];
  sa[0] = r[16];
  #pragma unroll
  for (int k = 1; k < 7; k++) sa[k] = fmaxf(sa[k - 1], r[16 + k]);
  float pooled[8];
  pooled[0] = fmaxf(core, q1);
  pooled[1] = fmaxf(fmaxf(core, q2), sa[0]);
  pooled[2] = fmaxf(fmaxf(core, q3), sa[1]);
  pooled[3] = fmaxf(fmaxf(core, q4), sa[2]);
  pooled[4] = fmaxf(fmaxf(core, q5), sa[3]);
  pooled[5] = fmaxf(fmaxf(core, q6), sa[4]);
  pooled[6] = fmaxf(fmaxf(core, q7), sa[5]);
  pooled[7] = fmaxf(core, sa[6]);

  const float4 cva = halo[prow + 7][(c8 << 1) + 2];   // raw score2 centers
  const float4 cvb = halo[prow + 7][(c8 << 1) + 3];
  const float cc[8] = {cva.x, cva.y, cva.z, cva.w, cvb.x, cvb.y, cvb.z, cvb.w};
  #pragma unroll
  for (int j = 0; j < 8; j++) {
    if ((mbits >> j) & 1u) {
      const float s = cc[j];
      if (s == pooled[j] && s > 0.f) {
        int slot = atomicAdd(&s_cnt, 1);            // LDS atomic, ~4/tile
        if (slot < BCAP) {
          s_cv[slot] = s;
          s_ci[slot] = (ty0 + prow) * W + tx0 + (c8 << 3) + j;
        }
      }
    }
  }
  // per-wave dense partials: plain global stores, no barrier needed
  #pragma unroll
  for (int off = 32; off > 0; off >>= 1) {
    t1 += __shfl_down(t1, off);
    mcnt += __shfl_down(mcnt, off);
  }
  if ((tid & 63) == 0) {
    ws->pt1[t * 4 + (tid >> 6)] = t1;
    ws->pmc[t * 4 + (tid >> 6)] = mcnt;
  }
  __syncthreads();
  // flush candidates + count (stored, not accumulated -> no pre-zero needed)
  int cnt = s_cnt; if (cnt > BCAP) cnt = BCAP;
  if (tid == 0) ws->tile_cnt[t] = cnt;
  if (tid < cnt) {
    ws->tile_val[t * BCAP + tid] = s_cv[tid];
    ws->tile_idx[t * BCAP + tid] = s_ci[tid];
  }
}

// One block per image: sum partials, scan tile counts, compact candidates,
// init corr, write rank-kernel float4 pad.
__global__ __launch_bounds__(256) void k_compact(WS* __restrict__ ws) {
  const int b = blockIdx.x;
  const int tid = threadIdx.x;
  const int lane = tid & 63, w = tid >> 6;
  __shared__ double sF[4];
  __shared__ int    sI[4];
  __shared__ int    wt[4];

  double tsum = 0.0; int msum = 0;
  for (int j = tid; j < 2048; j += 256) {
    tsum += (double)ws->pt1[b * 2048 + j];
    msum += ws->pmc[b * 2048 + j];
  }
  #pragma unroll
  for (int off = 32; off > 0; off >>= 1) {
    tsum += __shfl_down(tsum, off);
    msum += __shfl_down(msum, off);
  }
  if (lane == 0) { sF[w] = tsum; sI[w] = msum; }

  const int tg = b * 512 + 2 * tid;
  int c0 = ws->tile_cnt[tg];     if (c0 > BCAP) c0 = BCAP;
  int c1 = ws->tile_cnt[tg + 1]; if (c1 > BCAP) c1 = BCAP;
  const int pairs = c0 + c1;
  int v = pairs;
  #pragma unroll
  for (int off = 1; off < 64; off <<= 1) {
    int u = __shfl_up(v, off);
    if (lane >= off) v += u;
  }
  if (lane == 63) wt[w] = v;
  __syncthreads();
  if (tid == 0) {
    ws->term1[b] = (sF[0] + sF[1]) + (sF[2] + sF[3]);
    ws->masksum[b] = (unsigned int)(sI[0] + sI[1] + sI[2] + sI[3]);
    ws->corr[b] = 0.0;
  }
  int wo = 0;
  #pragma unroll
  for (int k = 0; k < 4; k++) if (k < w) wo += wt[k];
  const int excl = v - pairs + wo;
  float* dv = ws->ccand_val + b * CAP;
  int*   di = ws->ccand_idx + b * CAP;
  if (tid == 255) {
    int tot = excl + pairs;
    if (tot > CAP) tot = CAP;
    ws->cand_count[b] = tot;
    #pragma unroll
    for (int u = 0; u < 3; u++)              // float4 pad for rank kernel
      if (tot + u < CAP) dv[tot + u] = 0.f;
  }
  const float* sv0 = ws->tile_val + (size_t)tg * BCAP;
  const int*   si0 = ws->tile_idx + (size_t)tg * BCAP;
  for (int j = 0; j < c0; j++) {
    int o = excl + j;
    if (o < CAP) { dv[o] = sv0[j]; di[o] = si0[j]; }
  }
  for (int j = 0; j < c1; j++) {
    int o = excl + c0 + j;
    if (o < CAP) { dv[o] = sv0[BCAP + j]; di[o] = si0[BCAP + j]; }
  }
}

// Fused exact-rank + stamp: 64 cands/block, 4 waves split the j-scan 4-way.
__global__ __launch_bounds__(256, 4) void k_rankstamp(const float* __restrict__ score1,
                                                      const int* __restrict__ mask,
                                                      WS* __restrict__ ws) {
  // XCD swizzle: same-image blocks on same XCD (1024 = 8*128)
  const int blk = (blockIdx.x & 7) * 128 + (blockIdx.x >> 3);
  const int b = blk >> 6;
  const int slice = blk & 63;
  int n = ws->cand_count[b]; if (n > CAP) n = CAP;
  const int i0 = slice << 6;
  if (i0 >= n) return;
  __shared__ __align__(16) float sval[CAP];
  __shared__ __align__(16) int   sidx[CAP];
  __shared__ int   s_prank[4][64];
  __shared__ int   s_keys[64];
  __shared__ int   s_nk;
  __shared__ float cred[4];
  const int tid = threadIdx.x;
  const int nf4 = (n + 3) >> 2;

  const float4* gv = (const float4*)(ws->ccand_val + b * CAP);
  const int4*   gi = (const int4*)(ws->ccand_idx + b * CAP);
  for (int j = tid; j < nf4; j += 256) {
    ((float4*)sval)[j] = gv[j];
    ((int4*)sidx)[j]   = gi[j];
  }
  __syncthreads();

  const int w = tid >> 6, l = tid & 63;
  const float vi = sval[i0 + l];
  const int   xi = sidx[i0 + l];
  const int q = (nf4 + 3) >> 2;
  int lo = w * q; if (lo > nf4) lo = nf4;
  int hi = lo + q; if (hi > nf4) hi = nf4;
  int rank = 0;
  int j = lo;
  for (; j + 4 <= hi; j += 4) {
    #pragma unroll
    for (int u = 0; u < 4; u++) {
      const float4 v = ((const float4*)sval)[j + u];
      const int4  iv = ((const int4*)sidx)[j + u];
      rank += (v.x > vi) + (v.y > vi) + (v.z > vi) + (v.w > vi);
      rank += (v.x == vi && iv.x < xi);
      rank += (v.y == vi && iv.y < xi);
      rank += (v.z == vi && iv.z < xi);
      rank += (v.w == vi && iv.w < xi);
    }
  }
  for (; j < hi; j++) {
    const float4 v = ((const float4*)sval)[j];
    const int4  iv = ((const int4*)sidx)[j];
    rank += (v.x > vi) + (v.y > vi) + (v.z > vi) + (v.w > vi);
    rank += (v.x == vi && iv.x < xi);
    rank += (v.y == vi && iv.y < xi);
    rank += (v.z == vi && iv.z < xi);
    rank += (v.w == vi && iv.w < xi);
  }
  s_prank[w][l] = rank;
  __syncthreads();

  if (tid < 64) {
    const int rtot = s_prank[0][tid] + s_prank[1][tid] + s_prank[2][tid] + s_prank[3][tid];
    const bool sel = (i0 + tid < n) && (rtot < TOPK);
    const unsigned long long bal = __ballot(sel);
    if (sel) {
      const int pos = __popcll(bal & ((1ull << tid) - 1ull));
      s_keys[pos] = sidx[i0 + tid];
    }
    if (tid == 0) s_nk = (int)__popcll(bal);
  }
  __syncthreads();
  const int nk = s_nk;

  float contrib = 0.f;
  const int sub = tid & 7;
  const size_t ib2 = (size_t)b * ((size_t)H * W);
  #pragma unroll
  for (int rnd = 0; rnd < 2; rnd++) {
    const int k = (tid >> 3) + (rnd << 5);
    if (k < nk && sub < 7) {
      const int ck = s_keys[k];
      const int cy = ck >> 10, cx = ck & 1023;
      const int py = cy + sub - 3;
      const float wy = GW[sub] * ((py >= 0 && py < H) ? 1.f : 0.f);
      const int pyc = min(max(py, 0), H - 1);
      const float* s1r = score1 + ib2 + (size_t)pyc * W;
      const int*   mr  = mask   + ib2 + (size_t)pyc * W;
      #pragma unroll
      for (int dx = -3; dx <= 3; dx++) {
        const int px = cx + dx;
        const float wv = wy * GW[dx + 3] * ((px >= 0 && px < W) ? 1.f : 0.f);
        const int pxc = min(max(px, 0), W - 1);
        const float mf = (mr[pxc] != 0) ? 1.f : 0.f;
        contrib += mf * wv * (wv - 2.f * s1r[pxc]);
      }
    }
  }
  #pragma unroll
  for (int off = 32; off > 0; off >>= 1) contrib += __shfl_down(contrib, off);
  if ((tid & 63) == 0) cred[tid >> 6] = contrib;
  __syncthreads();
  if (tid == 0)
    atomicAdd(&ws->corr[b], (double)((cred[0] + cred[1]) + (cred[2] + cred[3])));
}

__global__ void k_final(WS* __restrict__ ws, float* __restrict__ out) {
  const int t = threadIdx.x;
  double v = 0.0;
  if (t < BATCH) {
    double denom = (double)ws->masksum[t];
    if (denom < 1e-8) denom = 1e-8;
    v = (ws->term1[t] + ws->corr[t]) / denom;
  }
  #pragma unroll
  for (int off = 32; off > 0; off >>= 1) v += __shfl_down(v, off);
  if (t == 0) out[0] = (float)(v / BATCH);
}

extern "C" void kernel_launch(void* const* d_in, const int* in_sizes, int n_in,
                              void* d_out, int out_size, void* d_ws, size_t ws_size,
                              hipStream_t stream) {
  const float* score1 = (const float*)d_in[0];
  const float* score2 = (const float*)d_in[1];
  const int*   mask   = (const int*)d_in[2];
  float* out = (float*)d_out;
  WS* ws = (WS*)d_ws;

  k_nms<<<NTILES, 256, 0, stream>>>(score1, score2, mask, ws);
  k_compact<<<BATCH, 256, 0, stream>>>(ws);
  k_rankstamp<<<BATCH * 64, 256, 0, stream>>>(score1, mask, ws);
  k_final<<<1, 64, 0, stream>>>(ws, out);
}